// Round 7
// baseline (717.785 us; speedup 1.0000x reference)
//
#include <hip/hip_runtime.h>
#include <hip/hip_bf16.h>
#include <stdint.h>

#define NROWS 131072
#define EPSBN 1e-5f
#define LEAKK 0.33f

typedef __bf16 bf16x8_t __attribute__((ext_vector_type(8)));
typedef float  f32x4_t  __attribute__((ext_vector_type(4)));

__device__ __forceinline__ float leaky_f(float x) { return fmaxf(x, LEAKK * x); }

#define GLDS16(g, l)                                                          \
    __builtin_amdgcn_global_load_lds(                                         \
        (const __attribute__((address_space(1))) void*)(g),                   \
        (__attribute__((address_space(3))) void*)(l), 16, 0, 0)

#define CFENCE() asm volatile("" ::: "memory")

// Gather-GEMM conv, 512-thread blocks for 16 waves/CU.
// r6 evidence: OccupancyPercent 21% = 8 waves/CU, limited by LDS (72KB slab
// at 256 thr/block = 2 blocks/CU), NOT VGPR (92 allows 4 waves/SIMD). The
// k-loop is gather-latency x outstanding-fill bound (~151MB of random 64B
// granules/conv at ~3.8 TB/s effective; all throughput models give <7us vs
// 37us observed). 512-thread blocks serve 8 waves from the same 72KB ->
// 2 blocks/CU = 16 waves/CU = 2x outstanding fills. Per-wave code unchanged
// (r1/r5's proven depth-1 reg-gather body). Raw acc out; BN in bnact (the
// grid-barrier fusion line r2-r6 is abandoned: barrier protocol costs more
// than the 6us/stage elementwise dispatches it replaces).
__global__ __launch_bounds__(512, 4) void conv_kernel(
    const __bf16* __restrict__ src,      // (NROWS+1) x 64, row NROWS = zeros
    const int* __restrict__ cidxT,       // [9][NROWS] premasked (masked->NROWS)
    const __bf16* __restrict__ wt,       // [9][64 d][64 c]
    __bf16* __restrict__ dst,
    float* __restrict__ stat_out)
{
    __shared__ char Bw[9][8192];         // 72KB shared by 8 waves

    const int tid  = threadIdx.x;
    const int lane = tid & 63;
    const int wv   = tid >> 6;                 // 0..7
    const int quad = lane >> 4;
    const int l15  = lane & 15;
    const int row0 = blockIdx.x << 9;          // 512 rows/block
    const int srow = tid >> 3;                 // staging row 0..63
    const int cg   = (tid & 7) ^ (srow & 7);   // swizzled global chunk
    const int ldsl = (tid & 448) << 4;         // wave-uniform lds base (wv*1024)
    const int sxor = l15 & 7;

    const char* srcb = (const char*)src;
    const char* wtb  = (const char*)wt;

    f32x4_t acc[4][4];
#pragma unroll
    for (int mt = 0; mt < 4; ++mt)
#pragma unroll
        for (int nt = 0; nt < 4; ++nt)
            acc[mt][nt] = (f32x4_t){0.f, 0.f, 0.f, 0.f};

    const int ibase = row0 + (wv << 6) + l15;  // wave row, + mt*16 per mt
    const unsigned qofs = (unsigned)(quad << 4);

    // ---- prologue: idx k=0,1 then all 9 B tiles (one GLDS per tap:
    // 512 lanes x 16B = 8KB; dest linear = tid*16, src chunk cg^(row&7)) ----
    int ixv[2][4];
#pragma unroll
    for (int mt = 0; mt < 4; ++mt) ixv[0][mt] = cidxT[ibase + (mt << 4)];
#pragma unroll
    for (int mt = 0; mt < 4; ++mt) ixv[1][mt] = cidxT[NROWS + ibase + (mt << 4)];
    CFENCE();
#pragma unroll
    for (int k = 0; k < 9; ++k)
        GLDS16(wtb + (k << 13) + (srow << 7) + (cg << 4), &Bw[k][ldsl]);
    CFENCE();
    asm volatile("s_waitcnt vmcnt(0)" ::: "memory");  // B + idx retired
    __builtin_amdgcn_s_barrier();                     // B visible to all
    CFENCE();

    // ---- A[0] into registers ----
    bf16x8_t areg[2][4][2];
#pragma unroll
    for (int mt = 0; mt < 4; ++mt) {
        unsigned vo = ((unsigned)ixv[0][mt] << 7) + qofs;
#pragma unroll
        for (int ks = 0; ks < 2; ++ks)
            areg[0][mt][ks] = *(const bf16x8_t*)(srcb + vo + (ks << 6));
    }
    CFENCE();

    // ---- k-loop: issue idx[k+2], A[k+1]; compute A[k]. No barriers. ----
#pragma unroll
    for (int k = 0; k < 9; ++k) {
        if (k < 7) {
#pragma unroll
            for (int mt = 0; mt < 4; ++mt)
                ixv[k & 1][mt] = cidxT[(k + 2) * NROWS + ibase + (mt << 4)];
        }
        if (k < 8) {
#pragma unroll
            for (int mt = 0; mt < 4; ++mt) {
                unsigned vo = ((unsigned)ixv[(k + 1) & 1][mt] << 7) + qofs;
#pragma unroll
                for (int ks = 0; ks < 2; ++ks)
                    areg[(k + 1) & 1][mt][ks] =
                        *(const bf16x8_t*)(srcb + vo + (ks << 6));
            }
        }
        CFENCE();
        bf16x8_t bq[4][2];
#pragma unroll
        for (int ks = 0; ks < 2; ++ks) {
            const int slot = ((quad | (ks << 2)) ^ sxor) << 4;
#pragma unroll
            for (int nt = 0; nt < 4; ++nt)
                bq[nt][ks] = *(const bf16x8_t*)
                    &Bw[k][(((nt << 4) + l15) << 7) + slot];
        }
        __builtin_amdgcn_s_setprio(1);
#pragma unroll
        for (int ks = 0; ks < 2; ++ks)
#pragma unroll
            for (int mt = 0; mt < 4; ++mt)
#pragma unroll
                for (int nt = 0; nt < 4; ++nt)
                    acc[mt][nt] = __builtin_amdgcn_mfma_f32_16x16x32_bf16(
                        areg[k & 1][mt][ks], bq[nt][ks], acc[mt][nt], 0, 0, 0);
        __builtin_amdgcn_s_setprio(0);
        CFENCE();
    }

    // ---- store raw acc (D layout: row = quad*4+reg, col = lane&15) ----
#pragma unroll
    for (int mt = 0; mt < 4; ++mt) {
        int rowb = row0 + (wv << 6) + (mt << 4) + (quad << 2);
#pragma unroll
        for (int nt = 0; nt < 4; ++nt) {
            int col = (nt << 4) + l15;
#pragma unroll
            for (int r = 0; r < 4; ++r)
                dst[((size_t)(rowb + r) << 6) + col] = (__bf16)acc[mt][nt][r];
        }
    }
    // ---- stats; red[] aliases Bw (k-loop fully consumed) ----
    float* red = (float*)Bw;
    __syncthreads();
    if (tid < 128) red[tid] = 0.f;
    __syncthreads();
#pragma unroll
    for (int nt = 0; nt < 4; ++nt) {
        float s = 0.f, q = 0.f;
#pragma unroll
        for (int mt = 0; mt < 4; ++mt)
#pragma unroll
            for (int r = 0; r < 4; ++r) { float v = acc[mt][nt][r]; s += v; q += v * v; }
        s += __shfl_xor(s, 16); s += __shfl_xor(s, 32);
        q += __shfl_xor(q, 16); q += __shfl_xor(q, 32);
        if (lane < 16) {
            atomicAdd(&red[(nt << 4) + lane], s);
            atomicAdd(&red[64 + (nt << 4) + lane], q);
        }
    }
    __syncthreads();
    if (tid < 128) atomicAdd(&stat_out[tid], red[tid]);
}

// in-place y = leaky(bn(y)) on bf16
__global__ __launch_bounds__(256) void bnact_kernel(
    __bf16* __restrict__ y, const float* __restrict__ stat,
    const float* __restrict__ gamma, const float* __restrict__ beta)
{
    __shared__ float sc[64], sh[64];
    int tid = threadIdx.x;
    if (tid < 64) {
        float m = stat[tid] * (1.f / NROWS);
        float v = stat[64 + tid] * (1.f / NROWS) - m * m;
        float s = gamma[tid] * rsqrtf(v + EPSBN);
        sc[tid] = s;
        sh[tid] = beta[tid] - m * s;
    }
    __syncthreads();
    size_t base = ((((size_t)blockIdx.x << 8) | tid) << 3);
    int c0 = (int)(base & 63);
    bf16x8_t hv = *(bf16x8_t*)(y + base);
#pragma unroll
    for (int j = 0; j < 8; ++j) {
        float f = (float)hv[j];
        f = leaky_f(f * sc[c0 + j] + sh[c0 + j]);
        hv[j] = (__bf16)f;
    }
    *(bf16x8_t*)(y + base) = hv;
}

// x_new = leaky(bn2(z) + x). Residual stream is bf16-only (xh). Block 0 reads
// feat (fp32); final block writes d_out (fp32) and skips the xh write.
__global__ __launch_bounds__(256) void resid_kernel(
    const __bf16* __restrict__ z, const float* __restrict__ featin,
    __bf16* __restrict__ xh, float* __restrict__ dout,
    const float* __restrict__ stat, const float* __restrict__ gamma,
    const float* __restrict__ beta, int isfirst, int isfinal)
{
    __shared__ float sc[64], sh[64];
    int tid = threadIdx.x;
    if (tid < 64) {
        float m = stat[tid] * (1.f / NROWS);
        float v = stat[64 + tid] * (1.f / NROWS) - m * m;
        float s = gamma[tid] * rsqrtf(v + EPSBN);
        sc[tid] = s;
        sh[tid] = beta[tid] - m * s;
    }
    __syncthreads();
    size_t base = ((((size_t)blockIdx.x << 8) | tid) << 3);
    int c0 = (int)(base & 63);
    bf16x8_t zv = *(const bf16x8_t*)(z + base);
    float xv[8];
    if (isfirst) {
        float4 xa = *(const float4*)(featin + base);
        float4 xb = *(const float4*)(featin + base + 4);
#pragma unroll
        for (int j = 0; j < 4; ++j) { xv[j] = (&xa.x)[j]; xv[4 + j] = (&xb.x)[j]; }
    } else {
        bf16x8_t xr = *(const bf16x8_t*)(xh + base);
#pragma unroll
        for (int j = 0; j < 8; ++j) xv[j] = (float)xr[j];
    }
    float o[8];
#pragma unroll
    for (int j = 0; j < 8; ++j)
        o[j] = leaky_f((float)zv[j] * sc[c0 + j] + sh[c0 + j] + xv[j]);
    if (isfinal) {
        *(float4*)(dout + base)     = make_float4(o[0], o[1], o[2], o[3]);
        *(float4*)(dout + base + 4) = make_float4(o[4], o[5], o[6], o[7]);
    } else {
        bf16x8_t h;
#pragma unroll
        for (int j = 0; j < 8; ++j) h[j] = (__bf16)o[j];
        *(bf16x8_t*)(xh + base) = h;
    }
}

// once-per-call prep: features->bf16 mirror, weights->transposed bf16, zero
// stats, premasked transposed indices cidxT[k][n] (masked-out -> NROWS),
// zero sentinel rows. Mask encoding detect: center (k=4) always True ->
// raw byte 13 nonzero iff byte-encoded; zero if int32/float32-encoded.
__global__ __launch_bounds__(256) void prep_kernel(
    const float* __restrict__ feat, const float* __restrict__ w1,
    const float* __restrict__ w2, const int* __restrict__ nidx,
    const unsigned char* __restrict__ mraw,
    __bf16* __restrict__ fh, __bf16* __restrict__ yh,
    __bf16* __restrict__ wtp, int* __restrict__ cidxT,
    float* __restrict__ stats)
{
    size_t t = ((size_t)blockIdx.x << 8) | threadIdx.x;
    if (t < 1024) stats[t] = 0.f;
    if (t < 64) {   // zero sentinel rows
        fh[(size_t)NROWS * 64 + t] = (__bf16)0.f;
        yh[(size_t)NROWS * 64 + t] = (__bf16)0.f;
    }
    if (t < 1048576) {  // features: 8 floats -> 8 bf16 per thread
        size_t i = t << 3;
        float4 a = *(const float4*)(feat + i);
        float4 b = *(const float4*)(feat + i + 4);
        bf16x8_t h;
        h[0] = (__bf16)a.x; h[1] = (__bf16)a.y; h[2] = (__bf16)a.z; h[3] = (__bf16)a.w;
        h[4] = (__bf16)b.x; h[5] = (__bf16)b.y; h[6] = (__bf16)b.z; h[7] = (__bf16)b.w;
        *(bf16x8_t*)(fh + i) = h;
    }
    if (t < 294912) {   // wtp[cv][b][k][d][c] = w[b][k][c][d]
        int o = (int)t;
        int c = o & 63, d = (o >> 6) & 63;
        int kk = o >> 12;              // 0..71
        int k = kk % 9, bb = (kk / 9) & 3, cv = kk / 36;
        const float* w = cv ? w2 : w1;
        float v = w[((size_t)((bb * 9 + k) * 64 + c) << 6) + d];
        wtp[o] = (__bf16)v;
    }
    if (t < NROWS) {    // cidxT: one thread per row n, 9 entries
        int n = (int)t;
        bool benc = (mraw[13] != 0);
        const unsigned int* mw = (const unsigned int*)mraw;
#pragma unroll
        for (int j = 0; j < 9; ++j) {
            int e = n * 9 + j;
            bool m = benc ? (mraw[e] != 0) : (mw[e] != 0u);
            cidxT[j * NROWS + n] = m ? nidx[e] : NROWS;
        }
    }
}

extern "C" void kernel_launch(void* const* d_in, const int* in_sizes, int n_in,
                              void* d_out, int out_size, void* d_ws, size_t ws_size,
                              hipStream_t stream) {
    const float* feat = (const float*)d_in[0];
    const int* nidx = (const int*)d_in[1];
    const unsigned char* mraw = (const unsigned char*)d_in[2];
    const float* w1 = (const float*)d_in[3];
    const float* g1 = (const float*)d_in[4];
    const float* b1 = (const float*)d_in[5];
    const float* w2 = (const float*)d_in[6];
    const float* g2 = (const float*)d_in[7];
    const float* b2 = (const float*)d_in[8];
    float* out = (float*)d_out;

    char* ws = (char*)d_ws;
    __bf16* xh    = (__bf16*)ws;                       // (N+1)x64 bf16 residual
    __bf16* yh    = (__bf16*)(ws + 17825792);          // (N+1)x64 bf16 conv1 out
    __bf16* zh    = (__bf16*)(ws + 35651584);          // N x64 bf16 conv2 out
    __bf16* wtp   = (__bf16*)(ws + 53477376);          // 0.59 MB transposed weights
    float*  stats = (float*)(ws + 54525952);           // 8 stages x 128 floats
    int*    cidxT = (int*)(ws + 54591488);             // 4.72 MB premasked idx^T

    prep_kernel<<<4096, 256, 0, stream>>>(feat, w1, w2, nidx, mraw,
                                          xh, yh, wtp, cidxT, stats);

    for (int b = 0; b < 4; ++b) {
        conv_kernel<<<256, 512, 0, stream>>>(
            xh, cidxT, wtp + (size_t)b * 9 * 4096,
            yh, stats + (size_t)(2 * b) * 128);
        bnact_kernel<<<4096, 256, 0, stream>>>(
            yh, stats + (size_t)(2 * b) * 128, g1 + b * 64, b1 + b * 64);
        conv_kernel<<<256, 512, 0, stream>>>(
            yh, cidxT, wtp + (size_t)(4 + b) * 9 * 4096,
            zh, stats + (size_t)(2 * b + 1) * 128);
        resid_kernel<<<4096, 256, 0, stream>>>(
            zh, feat, xh, out,
            stats + (size_t)(2 * b + 1) * 128, g2 + b * 64, b2 + b * 64,
            (b == 0) ? 1 : 0, (b == 3) ? 1 : 0);
    }
}

// Round 8
// 355.360 us; speedup vs baseline: 2.0199x; 2.0199x over previous
//
#include <hip/hip_runtime.h>
#include <hip/hip_bf16.h>
#include <stdint.h>

#define NROWS 131072
#define EPSBN 1e-5f
#define LEAKK 0.33f
#define NCOPY 8

typedef __bf16 bf16x8_t __attribute__((ext_vector_type(8)));
typedef float  f32x4_t  __attribute__((ext_vector_type(4)));

__device__ __forceinline__ float leaky_f(float x) { return fmaxf(x, LEAKK * x); }

#define GLDS16(g, l)                                                          \
    __builtin_amdgcn_global_load_lds(                                         \
        (const __attribute__((address_space(1))) void*)(g),                   \
        (__attribute__((address_space(3))) void*)(l), 16, 0, 0)

#define CFENCE() asm volatile("" ::: "memory")

// Gather-GEMM conv at 16 waves/CU.
// r7 lesson: 16 waves/CU needs <=128 VGPR; the 64x64 wave tile (64 acc regs)
// can't fit -> 32x64 tile: acc 32 + areg 16 + bq 32 + misc ~ 110 regs.
// B staged per-k double-buffered (2x8KB LDS) -> LDS cap 10 blocks/CU.
// Occupancy: min(VGPR 4 blk, LDS 10, waves 8) = 4 blocks x 4 waves =
// 16 waves/CU (2x r0's 8). A-gather volume unchanged (exclusive rows/wave).
// vmcnt ledger (queue per iter: [idx k+2 (2)][stage k+1 (2)][A k+1 (4)]):
// steady wait vmcnt(12), k=7 -> 10, k=8 -> 4; lgkm0+barrier closes the
// ds_read-vs-restage race (r0-proven). Stats scattered into 8 copies
// (r6 lesson: same-address RMW serialization); bnact/resid sum the copies.
__global__ __launch_bounds__(256, 4) void conv_kernel(
    const __bf16* __restrict__ src,      // (NROWS+1) x 64, row NROWS = zeros
    const int* __restrict__ cidxT,       // [9][NROWS] premasked (masked->NROWS)
    const __bf16* __restrict__ wt,       // [9][64 d][64 c]
    __bf16* __restrict__ dst,
    float* __restrict__ stat_out)        // NCOPY x 128
{
    __shared__ char Bw[2][8192];         // 16KB: per-k double-buffered B tap

    const int tid  = threadIdx.x;
    const int lane = tid & 63;
    const int wv   = tid >> 6;                 // 0..3
    const int quad = lane >> 4;
    const int l15  = lane & 15;
    const int row0 = blockIdx.x << 7;          // 128 rows/block
    const int srow = tid >> 3;                 // staging row 0..31
    const int cg   = (tid & 7) ^ (srow & 7);   // swizzled global chunk
    const int ldsl = (tid & 192) << 4;         // wave-uniform lds sub-base
    const int sxor = l15 & 7;

    const char* srcb = (const char*)src;
    const char* wtb  = (const char*)wt;

    f32x4_t acc[2][4];
#pragma unroll
    for (int mt = 0; mt < 2; ++mt)
#pragma unroll
        for (int nt = 0; nt < 4; ++nt)
            acc[mt][nt] = (f32x4_t){0.f, 0.f, 0.f, 0.f};

    const int ibase = row0 + (wv << 5) + l15;  // wave rows: +0 / +16
    const unsigned qofs = (unsigned)(quad << 4);

    // ---- prologue: idx0, idx1; stage B0; A0 ----
    int ixv[2][2];
#pragma unroll
    for (int mt = 0; mt < 2; ++mt) ixv[0][mt] = cidxT[ibase + (mt << 4)];
#pragma unroll
    for (int mt = 0; mt < 2; ++mt) ixv[1][mt] = cidxT[NROWS + ibase + (mt << 4)];
    CFENCE();
#pragma unroll
    for (int i = 0; i < 2; ++i)
        GLDS16(wtb + (((i << 5) + srow) << 7) + (cg << 4),
               &Bw[0][(i << 12) + ldsl]);
    CFENCE();
    bf16x8_t areg[2][2][2];
#pragma unroll
    for (int mt = 0; mt < 2; ++mt) {          // A0 (compiler waits idx0)
        unsigned vo = ((unsigned)ixv[0][mt] << 7) + qofs;
#pragma unroll
        for (int ks = 0; ks < 2; ++ks)
            areg[0][mt][ks] = *(const bf16x8_t*)(srcb + vo + (ks << 6));
    }
    CFENCE();

    // ---- k-loop: idx[k+2] | stage B[k+1] | A[k+1] | wait | barrier |
    //      compute k | lgkm0 | barrier ----
#pragma unroll
    for (int k = 0; k < 9; ++k) {
        if (k < 7) {
#pragma unroll
            for (int mt = 0; mt < 2; ++mt)
                ixv[k & 1][mt] = cidxT[(k + 2) * NROWS + ibase + (mt << 4)];
        }
        CFENCE();
        if (k < 8) {
#pragma unroll
            for (int i = 0; i < 2; ++i)
                GLDS16(wtb + ((size_t)(k + 1) << 13)
                           + (((i << 5) + srow) << 7) + (cg << 4),
                       &Bw[(k + 1) & 1][(i << 12) + ldsl]);
        }
        CFENCE();
        if (k < 8) {
#pragma unroll
            for (int mt = 0; mt < 2; ++mt) {
                unsigned vo = ((unsigned)ixv[(k + 1) & 1][mt] << 7) + qofs;
#pragma unroll
                for (int ks = 0; ks < 2; ++ks)
                    areg[(k + 1) & 1][mt][ks] =
                        *(const bf16x8_t*)(srcb + vo + (ks << 6));
            }
        }
        CFENCE();
        // retire stage k, keep idx(k+2)+stage(k+1)+A(k+1) in flight
        if (k < 7)       asm volatile("s_waitcnt vmcnt(12)" ::: "memory");
        else if (k == 7) asm volatile("s_waitcnt vmcnt(10)" ::: "memory");
        else             asm volatile("s_waitcnt vmcnt(4)"  ::: "memory");
        __builtin_amdgcn_s_barrier();          // stage k visible to all
        bf16x8_t bq[4][2];
#pragma unroll
        for (int ks = 0; ks < 2; ++ks) {
            const int slot = ((quad | (ks << 2)) ^ sxor) << 4;
#pragma unroll
            for (int nt = 0; nt < 4; ++nt)
                bq[nt][ks] = *(const bf16x8_t*)
                    &Bw[k & 1][(((nt << 4) + l15) << 7) + slot];
        }
        __builtin_amdgcn_s_setprio(1);
#pragma unroll
        for (int ks = 0; ks < 2; ++ks)
#pragma unroll
            for (int mt = 0; mt < 2; ++mt)
#pragma unroll
                for (int nt = 0; nt < 4; ++nt)
                    acc[mt][nt] = __builtin_amdgcn_mfma_f32_16x16x32_bf16(
                        areg[k & 1][mt][ks], bq[nt][ks], acc[mt][nt], 0, 0, 0);
        __builtin_amdgcn_s_setprio(0);
        CFENCE();
        asm volatile("s_waitcnt lgkmcnt(0)" ::: "memory");
        __builtin_amdgcn_s_barrier();          // buf (k&1) safe to restage
        CFENCE();
    }

    // ---- store raw acc (D layout: row = quad*4+reg, col = lane&15) ----
#pragma unroll
    for (int mt = 0; mt < 2; ++mt) {
        int rowb = row0 + (wv << 5) + (mt << 4) + (quad << 2);
#pragma unroll
        for (int nt = 0; nt < 4; ++nt) {
            int col = (nt << 4) + l15;
#pragma unroll
            for (int r = 0; r < 4; ++r)
                dst[((size_t)(rowb + r) << 6) + col] = (__bf16)acc[mt][nt][r];
        }
    }
    // ---- stats; red[] aliases Bw ----
    float* red = (float*)Bw;
    __syncthreads();
    if (tid < 128) red[tid] = 0.f;
    __syncthreads();
#pragma unroll
    for (int nt = 0; nt < 4; ++nt) {
        float s = 0.f, q = 0.f;
#pragma unroll
        for (int mt = 0; mt < 2; ++mt)
#pragma unroll
            for (int r = 0; r < 4; ++r) { float v = acc[mt][nt][r]; s += v; q += v * v; }
        s += __shfl_xor(s, 16); s += __shfl_xor(s, 32);
        q += __shfl_xor(q, 16); q += __shfl_xor(q, 32);
        if (lane < 16) {
            atomicAdd(&red[(nt << 4) + lane], s);
            atomicAdd(&red[64 + (nt << 4) + lane], q);
        }
    }
    __syncthreads();
    if (tid < 128)
        atomicAdd(&stat_out[((blockIdx.x & (NCOPY - 1)) << 7) + tid], red[tid]);
}

// in-place y = leaky(bn(y)) on bf16; stat = NCOPY x 128 partial copies
__global__ __launch_bounds__(256) void bnact_kernel(
    __bf16* __restrict__ y, const float* __restrict__ stat,
    const float* __restrict__ gamma, const float* __restrict__ beta)
{
    __shared__ float sc[64], sh[64];
    int tid = threadIdx.x;
    if (tid < 128) {
        float s = 0.f;
#pragma unroll
        for (int c = 0; c < NCOPY; ++c) s += stat[(c << 7) + tid];
        ((float*)sc)[tid >= 64 ? 0 : 0] = 0.f;  // no-op to keep shape
        if (tid < 64) sc[tid] = s;              // raw sum in sc temporarily
        else          sh[tid - 64] = s;         // raw sumsq in sh
    }
    __syncthreads();
    if (tid < 64) {
        float m = sc[tid] * (1.f / NROWS);
        float v = sh[tid] * (1.f / NROWS) - m * m;
        float s = gamma[tid] * rsqrtf(v + EPSBN);
        sc[tid] = s;
        sh[tid] = beta[tid] - m * s;
    }
    __syncthreads();
    size_t base = ((((size_t)blockIdx.x << 8) | tid) << 3);
    int c0 = (int)(base & 63);
    bf16x8_t hv = *(bf16x8_t*)(y + base);
#pragma unroll
    for (int j = 0; j < 8; ++j) {
        float f = (float)hv[j];
        f = leaky_f(f * sc[c0 + j] + sh[c0 + j]);
        hv[j] = (__bf16)f;
    }
    *(bf16x8_t*)(y + base) = hv;
}

// x_new = leaky(bn2(z) + x). Residual stream is bf16-only (xh).
__global__ __launch_bounds__(256) void resid_kernel(
    const __bf16* __restrict__ z, const float* __restrict__ featin,
    __bf16* __restrict__ xh, float* __restrict__ dout,
    const float* __restrict__ stat, const float* __restrict__ gamma,
    const float* __restrict__ beta, int isfirst, int isfinal)
{
    __shared__ float sc[64], sh[64];
    int tid = threadIdx.x;
    if (tid < 128) {
        float s = 0.f;
#pragma unroll
        for (int c = 0; c < NCOPY; ++c) s += stat[(c << 7) + tid];
        if (tid < 64) sc[tid] = s;
        else          sh[tid - 64] = s;
    }
    __syncthreads();
    if (tid < 64) {
        float m = sc[tid] * (1.f / NROWS);
        float v = sh[tid] * (1.f / NROWS) - m * m;
        float s = gamma[tid] * rsqrtf(v + EPSBN);
        sc[tid] = s;
        sh[tid] = beta[tid] - m * s;
    }
    __syncthreads();
    size_t base = ((((size_t)blockIdx.x << 8) | tid) << 3);
    int c0 = (int)(base & 63);
    bf16x8_t zv = *(const bf16x8_t*)(z + base);
    float xv[8];
    if (isfirst) {
        float4 xa = *(const float4*)(featin + base);
        float4 xb = *(const float4*)(featin + base + 4);
#pragma unroll
        for (int j = 0; j < 4; ++j) { xv[j] = (&xa.x)[j]; xv[4 + j] = (&xb.x)[j]; }
    } else {
        bf16x8_t xr = *(const bf16x8_t*)(xh + base);
#pragma unroll
        for (int j = 0; j < 8; ++j) xv[j] = (float)xr[j];
    }
    float o[8];
#pragma unroll
    for (int j = 0; j < 8; ++j)
        o[j] = leaky_f((float)zv[j] * sc[c0 + j] + sh[c0 + j] + xv[j]);
    if (isfinal) {
        *(float4*)(dout + base)     = make_float4(o[0], o[1], o[2], o[3]);
        *(float4*)(dout + base + 4) = make_float4(o[4], o[5], o[6], o[7]);
    } else {
        bf16x8_t h;
#pragma unroll
        for (int j = 0; j < 8; ++j) h[j] = (__bf16)o[j];
        *(bf16x8_t*)(xh + base) = h;
    }
}

// once-per-call prep (stats now 8 stages x NCOPY*128 = 8192 floats)
__global__ __launch_bounds__(256) void prep_kernel(
    const float* __restrict__ feat, const float* __restrict__ w1,
    const float* __restrict__ w2, const int* __restrict__ nidx,
    const unsigned char* __restrict__ mraw,
    __bf16* __restrict__ fh, __bf16* __restrict__ yh,
    __bf16* __restrict__ wtp, int* __restrict__ cidxT,
    float* __restrict__ stats)
{
    size_t t = ((size_t)blockIdx.x << 8) | threadIdx.x;
    if (t < 8192) stats[t] = 0.f;
    if (t < 64) {   // zero sentinel rows
        fh[(size_t)NROWS * 64 + t] = (__bf16)0.f;
        yh[(size_t)NROWS * 64 + t] = (__bf16)0.f;
    }
    if (t < 1048576) {  // features: 8 floats -> 8 bf16 per thread
        size_t i = t << 3;
        float4 a = *(const float4*)(feat + i);
        float4 b = *(const float4*)(feat + i + 4);
        bf16x8_t h;
        h[0] = (__bf16)a.x; h[1] = (__bf16)a.y; h[2] = (__bf16)a.z; h[3] = (__bf16)a.w;
        h[4] = (__bf16)b.x; h[5] = (__bf16)b.y; h[6] = (__bf16)b.z; h[7] = (__bf16)b.w;
        *(bf16x8_t*)(fh + i) = h;
    }
    if (t < 294912) {   // wtp[cv][b][k][d][c] = w[b][k][c][d]
        int o = (int)t;
        int c = o & 63, d = (o >> 6) & 63;
        int kk = o >> 12;              // 0..71
        int k = kk % 9, bb = (kk / 9) & 3, cv = kk / 36;
        const float* w = cv ? w2 : w1;
        float v = w[((size_t)((bb * 9 + k) * 64 + c) << 6) + d];
        wtp[o] = (__bf16)v;
    }
    if (t < NROWS) {    // cidxT: one thread per row n, 9 entries
        int n = (int)t;
        bool benc = (mraw[13] != 0);
        const unsigned int* mw = (const unsigned int*)mraw;
#pragma unroll
        for (int j = 0; j < 9; ++j) {
            int e = n * 9 + j;
            bool m = benc ? (mraw[e] != 0) : (mw[e] != 0u);
            cidxT[j * NROWS + n] = m ? nidx[e] : NROWS;
        }
    }
}

extern "C" void kernel_launch(void* const* d_in, const int* in_sizes, int n_in,
                              void* d_out, int out_size, void* d_ws, size_t ws_size,
                              hipStream_t stream) {
    const float* feat = (const float*)d_in[0];
    const int* nidx = (const int*)d_in[1];
    const unsigned char* mraw = (const unsigned char*)d_in[2];
    const float* w1 = (const float*)d_in[3];
    const float* g1 = (const float*)d_in[4];
    const float* b1 = (const float*)d_in[5];
    const float* w2 = (const float*)d_in[6];
    const float* g2 = (const float*)d_in[7];
    const float* b2 = (const float*)d_in[8];
    float* out = (float*)d_out;

    char* ws = (char*)d_ws;
    __bf16* xh    = (__bf16*)ws;                       // (N+1)x64 bf16 residual
    __bf16* yh    = (__bf16*)(ws + 17825792);          // (N+1)x64 bf16 conv1 out
    __bf16* zh    = (__bf16*)(ws + 35651584);          // N x64 bf16 conv2 out
    __bf16* wtp   = (__bf16*)(ws + 53477376);          // 0.59 MB transposed weights
    float*  stats = (float*)(ws + 54525952);           // 8 stages x 1024 floats
    int*    cidxT = (int*)(ws + 54591488);             // 4.72 MB premasked idx^T

    prep_kernel<<<4096, 256, 0, stream>>>(feat, w1, w2, nidx, mraw,
                                          xh, yh, wtp, cidxT, stats);

    for (int b = 0; b < 4; ++b) {
        conv_kernel<<<1024, 256, 0, stream>>>(
            xh, cidxT, wtp + (size_t)b * 9 * 4096,
            yh, stats + (size_t)(2 * b) * 1024);
        bnact_kernel<<<4096, 256, 0, stream>>>(
            yh, stats + (size_t)(2 * b) * 1024, g1 + b * 64, b1 + b * 64);
        conv_kernel<<<1024, 256, 0, stream>>>(
            yh, cidxT, wtp + (size_t)(4 + b) * 9 * 4096,
            zh, stats + (size_t)(2 * b + 1) * 1024);
        resid_kernel<<<4096, 256, 0, stream>>>(
            zh, feat, xh, out,
            stats + (size_t)(2 * b + 1) * 1024, g2 + b * 64, b2 + b * 64,
            (b == 0) ? 1 : 0, (b == 3) ? 1 : 0);
    }
}

// Round 9
// 335.650 us; speedup vs baseline: 2.1385x; 1.0587x over previous
//
#include <hip/hip_runtime.h>
#include <hip/hip_bf16.h>
#include <stdint.h>

#define NROWS 131072
#define EPSBN 1e-5f
#define LEAKK 0.33f
#define NCOPY 8

typedef __bf16 bf16x8_t __attribute__((ext_vector_type(8)));
typedef float  f32x4_t  __attribute__((ext_vector_type(4)));

__device__ __forceinline__ float leaky_f(float x) { return fmaxf(x, LEAKK * x); }

#define GLDS16(g, l)                                                          \
    __builtin_amdgcn_global_load_lds(                                         \
        (const __attribute__((address_space(1))) void*)(g),                   \
        (__attribute__((address_space(3))) void*)(l), 16, 0, 0)

#define CFENCE() asm volatile("" ::: "memory")

// r8 structure (31us/conv, 16 waves/CU, best=355us total): 32x64 wave tile,
// per-k double-buffered B (2x8KB), depth-1 reg A-gather, vmcnt ledger
// (steady 12 / k7 10 / k8 4), scattered stats (NCOPY copies).
// r9: bnact FUSED into conv2's gather (convbn_kernel): BN1 stats are
// complete at dispatch boundary; apply leaky(sc*a+sh) per gathered fragment
// in-register (VALUBusy was 3-5% -> transform hides under gather stalls).
// Masked neighbors (sentinel row) must contribute ZERO, not leaky(sh):
// shadow row indices at A-issue, cndmask transformed fragment to 0.

// ---- plain conv (conv1): raw acc out + scattered stats ----
__global__ __launch_bounds__(256, 4) void conv_kernel(
    const __bf16* __restrict__ src,      // (NROWS+1) x 64, row NROWS = zeros
    const int* __restrict__ cidxT,       // [9][NROWS] premasked (masked->NROWS)
    const __bf16* __restrict__ wt,       // [9][64 d][64 c]
    __bf16* __restrict__ dst,
    float* __restrict__ stat_out)        // NCOPY x 128
{
    __shared__ char Bw[2][8192];

    const int tid  = threadIdx.x;
    const int lane = tid & 63;
    const int wv   = tid >> 6;
    const int quad = lane >> 4;
    const int l15  = lane & 15;
    const int row0 = blockIdx.x << 7;
    const int srow = tid >> 3;
    const int cg   = (tid & 7) ^ (srow & 7);
    const int ldsl = (tid & 192) << 4;
    const int sxor = l15 & 7;

    const char* srcb = (const char*)src;
    const char* wtb  = (const char*)wt;

    f32x4_t acc[2][4];
#pragma unroll
    for (int mt = 0; mt < 2; ++mt)
#pragma unroll
        for (int nt = 0; nt < 4; ++nt)
            acc[mt][nt] = (f32x4_t){0.f, 0.f, 0.f, 0.f};

    const int ibase = row0 + (wv << 5) + l15;
    const unsigned qofs = (unsigned)(quad << 4);

    int ixv[2][2];
#pragma unroll
    for (int mt = 0; mt < 2; ++mt) ixv[0][mt] = cidxT[ibase + (mt << 4)];
#pragma unroll
    for (int mt = 0; mt < 2; ++mt) ixv[1][mt] = cidxT[NROWS + ibase + (mt << 4)];
    CFENCE();
#pragma unroll
    for (int i = 0; i < 2; ++i)
        GLDS16(wtb + (((i << 5) + srow) << 7) + (cg << 4),
               &Bw[0][(i << 12) + ldsl]);
    CFENCE();
    bf16x8_t areg[2][2][2];
#pragma unroll
    for (int mt = 0; mt < 2; ++mt) {
        unsigned vo = ((unsigned)ixv[0][mt] << 7) + qofs;
#pragma unroll
        for (int ks = 0; ks < 2; ++ks)
            areg[0][mt][ks] = *(const bf16x8_t*)(srcb + vo + (ks << 6));
    }
    CFENCE();

#pragma unroll
    for (int k = 0; k < 9; ++k) {
        if (k < 7) {
#pragma unroll
            for (int mt = 0; mt < 2; ++mt)
                ixv[k & 1][mt] = cidxT[(k + 2) * NROWS + ibase + (mt << 4)];
        }
        CFENCE();
        if (k < 8) {
#pragma unroll
            for (int i = 0; i < 2; ++i)
                GLDS16(wtb + ((size_t)(k + 1) << 13)
                           + (((i << 5) + srow) << 7) + (cg << 4),
                       &Bw[(k + 1) & 1][(i << 12) + ldsl]);
        }
        CFENCE();
        if (k < 8) {
#pragma unroll
            for (int mt = 0; mt < 2; ++mt) {
                unsigned vo = ((unsigned)ixv[(k + 1) & 1][mt] << 7) + qofs;
#pragma unroll
                for (int ks = 0; ks < 2; ++ks)
                    areg[(k + 1) & 1][mt][ks] =
                        *(const bf16x8_t*)(srcb + vo + (ks << 6));
            }
        }
        CFENCE();
        if (k < 7)       asm volatile("s_waitcnt vmcnt(12)" ::: "memory");
        else if (k == 7) asm volatile("s_waitcnt vmcnt(10)" ::: "memory");
        else             asm volatile("s_waitcnt vmcnt(4)"  ::: "memory");
        __builtin_amdgcn_s_barrier();
        bf16x8_t bq[4][2];
#pragma unroll
        for (int ks = 0; ks < 2; ++ks) {
            const int slot = ((quad | (ks << 2)) ^ sxor) << 4;
#pragma unroll
            for (int nt = 0; nt < 4; ++nt)
                bq[nt][ks] = *(const bf16x8_t*)
                    &Bw[k & 1][(((nt << 4) + l15) << 7) + slot];
        }
        __builtin_amdgcn_s_setprio(1);
#pragma unroll
        for (int ks = 0; ks < 2; ++ks)
#pragma unroll
            for (int mt = 0; mt < 2; ++mt)
#pragma unroll
                for (int nt = 0; nt < 4; ++nt)
                    acc[mt][nt] = __builtin_amdgcn_mfma_f32_16x16x32_bf16(
                        areg[k & 1][mt][ks], bq[nt][ks], acc[mt][nt], 0, 0, 0);
        __builtin_amdgcn_s_setprio(0);
        CFENCE();
        asm volatile("s_waitcnt lgkmcnt(0)" ::: "memory");
        __builtin_amdgcn_s_barrier();
        CFENCE();
    }

#pragma unroll
    for (int mt = 0; mt < 2; ++mt) {
        int rowb = row0 + (wv << 5) + (mt << 4) + (quad << 2);
#pragma unroll
        for (int nt = 0; nt < 4; ++nt) {
            int col = (nt << 4) + l15;
#pragma unroll
            for (int r = 0; r < 4; ++r)
                dst[((size_t)(rowb + r) << 6) + col] = (__bf16)acc[mt][nt][r];
        }
    }
    float* red = (float*)Bw;
    __syncthreads();
    if (tid < 128) red[tid] = 0.f;
    __syncthreads();
#pragma unroll
    for (int nt = 0; nt < 4; ++nt) {
        float s = 0.f, q = 0.f;
#pragma unroll
        for (int mt = 0; mt < 2; ++mt)
#pragma unroll
            for (int r = 0; r < 4; ++r) { float v = acc[mt][nt][r]; s += v; q += v * v; }
        s += __shfl_xor(s, 16); s += __shfl_xor(s, 32);
        q += __shfl_xor(q, 16); q += __shfl_xor(q, 32);
        if (lane < 16) {
            atomicAdd(&red[(nt << 4) + lane], s);
            atomicAdd(&red[64 + (nt << 4) + lane], q);
        }
    }
    __syncthreads();
    if (tid < 128)
        atomicAdd(&stat_out[((blockIdx.x & (NCOPY - 1)) << 7) + tid], red[tid]);
}

// ---- conv2 with fused BN1+leaky on the gathered A operand ----
__global__ __launch_bounds__(256, 4) void convbn_kernel(
    const __bf16* __restrict__ src,      // yh RAW (conv1 acc), sentinel zeros
    const int* __restrict__ cidxT,
    const __bf16* __restrict__ wt,
    __bf16* __restrict__ dst,
    float* __restrict__ stat_out,        // this conv's stats (NCOPY x 128)
    const float* __restrict__ stat_in,   // conv1 stats copies (NCOPY x 128)
    const float* __restrict__ gamma, const float* __restrict__ beta)
{
    __shared__ char Bw[2][8192];
    __shared__ float scsh[128];          // raw sums, then reused
    __shared__ float scD[64], shD[64];   // finalized BN1 scale/shift

    const int tid  = threadIdx.x;
    const int lane = tid & 63;
    const int wv   = tid >> 6;
    const int quad = lane >> 4;
    const int l15  = lane & 15;
    const int row0 = blockIdx.x << 7;
    const int srow = tid >> 3;
    const int cg   = (tid & 7) ^ (srow & 7);
    const int ldsl = (tid & 192) << 4;
    const int sxor = l15 & 7;

    const char* srcb = (const char*)src;
    const char* wtb  = (const char*)wt;

    f32x4_t acc[2][4];
#pragma unroll
    for (int mt = 0; mt < 2; ++mt)
#pragma unroll
        for (int nt = 0; nt < 4; ++nt)
            acc[mt][nt] = (f32x4_t){0.f, 0.f, 0.f, 0.f};

    const int ibase = row0 + (wv << 5) + l15;
    const unsigned qofs = (unsigned)(quad << 4);

    // idx k=0,1 + stage B0 (in flight across the BN-finalize dance)
    int ixv[2][2], ixs[2][2];
#pragma unroll
    for (int mt = 0; mt < 2; ++mt) ixv[0][mt] = cidxT[ibase + (mt << 4)];
#pragma unroll
    for (int mt = 0; mt < 2; ++mt) ixv[1][mt] = cidxT[NROWS + ibase + (mt << 4)];
    CFENCE();
#pragma unroll
    for (int i = 0; i < 2; ++i)
        GLDS16(wtb + (((i << 5) + srow) << 7) + (cg << 4),
               &Bw[0][(i << 12) + ldsl]);
    CFENCE();
    // finalize BN1 from conv1's scattered stat copies
    if (tid < 128) {
        float s = 0.f;
#pragma unroll
        for (int c = 0; c < NCOPY; ++c) s += stat_in[(c << 7) + tid];
        scsh[tid] = s;
    }
    __syncthreads();
    if (tid < 64) {
        float m = scsh[tid] * (1.f / NROWS);
        float v = scsh[64 + tid] * (1.f / NROWS) - m * m;
        float s = gamma[tid] * rsqrtf(v + EPSBN);
        scD[tid] = s;
        shD[tid] = beta[tid] - m * s;
    }
    __syncthreads();                     // scD/shD + B-stage ordering
    asm volatile("s_waitcnt vmcnt(0)" ::: "memory");
    __builtin_amdgcn_s_barrier();
    CFENCE();

    bf16x8_t areg[2][2][2];
#pragma unroll
    for (int mt = 0; mt < 2; ++mt) {
        ixs[0][mt] = ixv[0][mt];
        unsigned vo = ((unsigned)ixv[0][mt] << 7) + qofs;
#pragma unroll
        for (int ks = 0; ks < 2; ++ks)
            areg[0][mt][ks] = *(const bf16x8_t*)(srcb + vo + (ks << 6));
    }
    CFENCE();

#pragma unroll
    for (int k = 0; k < 9; ++k) {
        if (k < 7) {
#pragma unroll
            for (int mt = 0; mt < 2; ++mt)
                ixv[k & 1][mt] = cidxT[(k + 2) * NROWS + ibase + (mt << 4)];
        }
        CFENCE();
        if (k < 8) {
#pragma unroll
            for (int i = 0; i < 2; ++i)
                GLDS16(wtb + ((size_t)(k + 1) << 13)
                           + (((i << 5) + srow) << 7) + (cg << 4),
                       &Bw[(k + 1) & 1][(i << 12) + ldsl]);
        }
        CFENCE();
        if (k < 8) {
#pragma unroll
            for (int mt = 0; mt < 2; ++mt) {
                int ix = ixv[(k + 1) & 1][mt];
                ixs[(k + 1) & 1][mt] = ix;            // shadow for mask
                unsigned vo = ((unsigned)ix << 7) + qofs;
#pragma unroll
                for (int ks = 0; ks < 2; ++ks)
                    areg[(k + 1) & 1][mt][ks] =
                        *(const bf16x8_t*)(srcb + vo + (ks << 6));
            }
        }
        CFENCE();
        if (k < 7)       asm volatile("s_waitcnt vmcnt(12)" ::: "memory");
        else if (k == 7) asm volatile("s_waitcnt vmcnt(10)" ::: "memory");
        else             asm volatile("s_waitcnt vmcnt(4)"  ::: "memory");
        __builtin_amdgcn_s_barrier();
        // per-k BN constants for this lane's channels (transient regs)
        f32x4_t scq[2][2], shq[2][2];
#pragma unroll
        for (int ks = 0; ks < 2; ++ks) {
            int cb = (ks << 5) + (quad << 3);
            scq[ks][0] = *(const f32x4_t*)&scD[cb];
            scq[ks][1] = *(const f32x4_t*)&scD[cb + 4];
            shq[ks][0] = *(const f32x4_t*)&shD[cb];
            shq[ks][1] = *(const f32x4_t*)&shD[cb + 4];
        }
        // transform gathered A: leaky(sc*a+sh); masked rows -> 0
        bf16x8_t ta[2][2];
        const bf16x8_t zfrag = {};
#pragma unroll
        for (int mt = 0; mt < 2; ++mt) {
            bool dead = (ixs[k & 1][mt] == NROWS);
#pragma unroll
            for (int ks = 0; ks < 2; ++ks) {
                bf16x8_t a = areg[k & 1][mt][ks];
                bf16x8_t t;
#pragma unroll
                for (int j = 0; j < 8; ++j) {
                    float f = (float)a[j];
                    float y = fmaf(scq[ks][j >> 2][j & 3], f,
                                   shq[ks][j >> 2][j & 3]);
                    y = fmaxf(y, LEAKK * y);
                    t[j] = (__bf16)y;
                }
                ta[mt][ks] = dead ? zfrag : t;
            }
        }
        bf16x8_t bq[4][2];
#pragma unroll
        for (int ks = 0; ks < 2; ++ks) {
            const int slot = ((quad | (ks << 2)) ^ sxor) << 4;
#pragma unroll
            for (int nt = 0; nt < 4; ++nt)
                bq[nt][ks] = *(const bf16x8_t*)
                    &Bw[k & 1][(((nt << 4) + l15) << 7) + slot];
        }
        __builtin_amdgcn_s_setprio(1);
#pragma unroll
        for (int ks = 0; ks < 2; ++ks)
#pragma unroll
            for (int mt = 0; mt < 2; ++mt)
#pragma unroll
                for (int nt = 0; nt < 4; ++nt)
                    acc[mt][nt] = __builtin_amdgcn_mfma_f32_16x16x32_bf16(
                        ta[mt][ks], bq[nt][ks], acc[mt][nt], 0, 0, 0);
        __builtin_amdgcn_s_setprio(0);
        CFENCE();
        asm volatile("s_waitcnt lgkmcnt(0)" ::: "memory");
        __builtin_amdgcn_s_barrier();
        CFENCE();
    }

#pragma unroll
    for (int mt = 0; mt < 2; ++mt) {
        int rowb = row0 + (wv << 5) + (mt << 4) + (quad << 2);
#pragma unroll
        for (int nt = 0; nt < 4; ++nt) {
            int col = (nt << 4) + l15;
#pragma unroll
            for (int r = 0; r < 4; ++r)
                dst[((size_t)(rowb + r) << 6) + col] = (__bf16)acc[mt][nt][r];
        }
    }
    float* red = (float*)Bw;
    __syncthreads();
    if (tid < 128) red[tid] = 0.f;
    __syncthreads();
#pragma unroll
    for (int nt = 0; nt < 4; ++nt) {
        float s = 0.f, q = 0.f;
#pragma unroll
        for (int mt = 0; mt < 2; ++mt)
#pragma unroll
            for (int r = 0; r < 4; ++r) { float v = acc[mt][nt][r]; s += v; q += v * v; }
        s += __shfl_xor(s, 16); s += __shfl_xor(s, 32);
        q += __shfl_xor(q, 16); q += __shfl_xor(q, 32);
        if (lane < 16) {
            atomicAdd(&red[(nt << 4) + lane], s);
            atomicAdd(&red[64 + (nt << 4) + lane], q);
        }
    }
    __syncthreads();
    if (tid < 128)
        atomicAdd(&stat_out[((blockIdx.x & (NCOPY - 1)) << 7) + tid], red[tid]);
}

// x_new = leaky(bn2(z) + x). stat = NCOPY x 128 partial copies.
__global__ __launch_bounds__(256) void resid_kernel(
    const __bf16* __restrict__ z, const float* __restrict__ featin,
    __bf16* __restrict__ xh, float* __restrict__ dout,
    const float* __restrict__ stat, const float* __restrict__ gamma,
    const float* __restrict__ beta, int isfirst, int isfinal)
{
    __shared__ float sc[64], sh[64];
    int tid = threadIdx.x;
    if (tid < 128) {
        float s = 0.f;
#pragma unroll
        for (int c = 0; c < NCOPY; ++c) s += stat[(c << 7) + tid];
        if (tid < 64) sc[tid] = s;
        else          sh[tid - 64] = s;
    }
    __syncthreads();
    if (tid < 64) {
        float m = sc[tid] * (1.f / NROWS);
        float v = sh[tid] * (1.f / NROWS) - m * m;
        float s = gamma[tid] * rsqrtf(v + EPSBN);
        sc[tid] = s;
        sh[tid] = beta[tid] - m * s;
    }
    __syncthreads();
    size_t base = ((((size_t)blockIdx.x << 8) | tid) << 3);
    int c0 = (int)(base & 63);
    bf16x8_t zv = *(const bf16x8_t*)(z + base);
    float xv[8];
    if (isfirst) {
        float4 xa = *(const float4*)(featin + base);
        float4 xb = *(const float4*)(featin + base + 4);
#pragma unroll
        for (int j = 0; j < 4; ++j) { xv[j] = (&xa.x)[j]; xv[4 + j] = (&xb.x)[j]; }
    } else {
        bf16x8_t xr = *(const bf16x8_t*)(xh + base);
#pragma unroll
        for (int j = 0; j < 8; ++j) xv[j] = (float)xr[j];
    }
    float o[8];
#pragma unroll
    for (int j = 0; j < 8; ++j)
        o[j] = leaky_f((float)zv[j] * sc[c0 + j] + sh[c0 + j] + xv[j]);
    if (isfinal) {
        *(float4*)(dout + base)     = make_float4(o[0], o[1], o[2], o[3]);
        *(float4*)(dout + base + 4) = make_float4(o[4], o[5], o[6], o[7]);
    } else {
        bf16x8_t h;
#pragma unroll
        for (int j = 0; j < 8; ++j) h[j] = (__bf16)o[j];
        *(bf16x8_t*)(xh + base) = h;
    }
}

// once-per-call prep (stats 8 stages x NCOPY*128 = 8192 floats)
__global__ __launch_bounds__(256) void prep_kernel(
    const float* __restrict__ feat, const float* __restrict__ w1,
    const float* __restrict__ w2, const int* __restrict__ nidx,
    const unsigned char* __restrict__ mraw,
    __bf16* __restrict__ fh, __bf16* __restrict__ yh,
    __bf16* __restrict__ wtp, int* __restrict__ cidxT,
    float* __restrict__ stats)
{
    size_t t = ((size_t)blockIdx.x << 8) | threadIdx.x;
    if (t < 8192) stats[t] = 0.f;
    if (t < 64) {   // zero sentinel rows
        fh[(size_t)NROWS * 64 + t] = (__bf16)0.f;
        yh[(size_t)NROWS * 64 + t] = (__bf16)0.f;
    }
    if (t < 1048576) {  // features: 8 floats -> 8 bf16 per thread
        size_t i = t << 3;
        float4 a = *(const float4*)(feat + i);
        float4 b = *(const float4*)(feat + i + 4);
        bf16x8_t h;
        h[0] = (__bf16)a.x; h[1] = (__bf16)a.y; h[2] = (__bf16)a.z; h[3] = (__bf16)a.w;
        h[4] = (__bf16)b.x; h[5] = (__bf16)b.y; h[6] = (__bf16)b.z; h[7] = (__bf16)b.w;
        *(bf16x8_t*)(fh + i) = h;
    }
    if (t < 294912) {   // wtp[cv][b][k][d][c] = w[b][k][c][d]
        int o = (int)t;
        int c = o & 63, d = (o >> 6) & 63;
        int kk = o >> 12;              // 0..71
        int k = kk % 9, bb = (kk / 9) & 3, cv = kk / 36;
        const float* w = cv ? w2 : w1;
        float v = w[((size_t)((bb * 9 + k) * 64 + c) << 6) + d];
        wtp[o] = (__bf16)v;
    }
    if (t < NROWS) {    // cidxT: one thread per row n, 9 entries
        int n = (int)t;
        bool benc = (mraw[13] != 0);
        const unsigned int* mw = (const unsigned int*)mraw;
#pragma unroll
        for (int j = 0; j < 9; ++j) {
            int e = n * 9 + j;
            bool m = benc ? (mraw[e] != 0) : (mw[e] != 0u);
            cidxT[j * NROWS + n] = m ? nidx[e] : NROWS;
        }
    }
}

extern "C" void kernel_launch(void* const* d_in, const int* in_sizes, int n_in,
                              void* d_out, int out_size, void* d_ws, size_t ws_size,
                              hipStream_t stream) {
    const float* feat = (const float*)d_in[0];
    const int* nidx = (const int*)d_in[1];
    const unsigned char* mraw = (const unsigned char*)d_in[2];
    const float* w1 = (const float*)d_in[3];
    const float* g1 = (const float*)d_in[4];
    const float* b1 = (const float*)d_in[5];
    const float* w2 = (const float*)d_in[6];
    const float* g2 = (const float*)d_in[7];
    const float* b2 = (const float*)d_in[8];
    float* out = (float*)d_out;

    char* ws = (char*)d_ws;
    __bf16* xh    = (__bf16*)ws;                       // (N+1)x64 bf16 residual
    __bf16* yh    = (__bf16*)(ws + 17825792);          // (N+1)x64 bf16 conv1 raw
    __bf16* zh    = (__bf16*)(ws + 35651584);          // N x64 bf16 conv2 raw
    __bf16* wtp   = (__bf16*)(ws + 53477376);          // 0.59 MB transposed weights
    float*  stats = (float*)(ws + 54525952);           // 8 stages x 1024 floats
    int*    cidxT = (int*)(ws + 54591488);             // 4.72 MB premasked idx^T

    prep_kernel<<<4096, 256, 0, stream>>>(feat, w1, w2, nidx, mraw,
                                          xh, yh, wtp, cidxT, stats);

    for (int b = 0; b < 4; ++b) {
        // conv1 -> yh raw + stats(2b)
        conv_kernel<<<1024, 256, 0, stream>>>(
            xh, cidxT, wtp + (size_t)b * 9 * 4096,
            yh, stats + (size_t)(2 * b) * 1024);
        // conv2 with fused BN1+leaky on gathered A -> zh raw + stats(2b+1)
        convbn_kernel<<<1024, 256, 0, stream>>>(
            yh, cidxT, wtp + (size_t)(4 + b) * 9 * 4096,
            zh, stats + (size_t)(2 * b + 1) * 1024,
            stats + (size_t)(2 * b) * 1024, g1 + b * 64, b1 + b * 64);
        // resid: x_new = leaky(bn2(z) + x)
        resid_kernel<<<4096, 256, 0, stream>>>(
            zh, feat, xh, out,
            stats + (size_t)(2 * b + 1) * 1024, g2 + b * 64, b2 + b * 64,
            (b == 0) ? 1 : 0, (b == 3) ? 1 : 0);
    }
}

// Round 11
// 335.089 us; speedup vs baseline: 2.1421x; 1.0017x over previous
//
#include <hip/hip_runtime.h>
#include <hip/hip_bf16.h>
#include <stdint.h>

#define NROWS 131072
#define EPSBN 1e-5f
#define LEAKK 0.33f
#define NCOPY 8

typedef __bf16 bf16x8_t __attribute__((ext_vector_type(8)));
typedef float  f32x4_t  __attribute__((ext_vector_type(4)));
typedef int    i32x4_t  __attribute__((ext_vector_type(4)));

__device__ __forceinline__ float leaky_f(float x) { return fmaxf(x, LEAKK * x); }

#define GLDS16(g, l)                                                          \
    __builtin_amdgcn_global_load_lds(                                         \
        (const __attribute__((address_space(1))) void*)(g),                   \
        (__attribute__((address_space(3))) void*)(l), 16, 0, 0)

#define CFENCE() asm volatile("" ::: "memory")

// r11: conv1 gathers int8 rows (64B = ONE sector txn vs two for bf16) with
// PER-ROW dynamic scales, dequantized in-register to bf16 and fed to the
// unchanged bf16 MFMA with bf16 weights. r10's failure decomposed: fixed
// SA=15.875 act-quant noise (~0.25 absmax) dominated; per-row scales are
// 2.25x finer AND clip-free; bf16 weights remove wquant noise entirely.
// A-fragment ch mapping from a contiguous 16B load = quad*16+ks*8+j, baked
// into conv1's weight layout (wtp1 permuted in prep). Scale table (524KB)
// is L2-resident -> scale loads don't consume L3 gather txns.
// Ledger unchanged from proven r8 (8 loads/iter): steady 12 / k7 10 / k8 4.

__device__ __forceinline__ void dequant16(i32x4_t rw, float sf,
                                          bf16x8_t& a0, bf16x8_t& a1) {
#pragma unroll
    for (int d = 0; d < 4; ++d) {
        int w = rw[d];
#pragma unroll
        for (int b = 0; b < 4; ++b) {
            int v = (w << ((3 - b) << 3)) >> 24;      // sign-extended byte b
            float f = (float)v * sf;
            int j = (d << 2) + b;                     // ch offset 0..15
            if (j < 8) a0[j] = (__bf16)f;
            else       a1[j & 7] = (__bf16)f;
        }
    }
}

// ---- conv1: int8+scale gather, bf16 MFMA (permuted wtp1) ----
__global__ __launch_bounds__(256, 4) void convq_kernel(
    const char* __restrict__ srcq,       // (NROWS+1) x 64 int8, sentinel zeros
    const float* __restrict__ sxa,       // (NROWS+1) per-row dequant scales
    const int* __restrict__ cidxT,       // [9][NROWS] premasked (masked->NROWS)
    const __bf16* __restrict__ wt,       // wtp1: [9][64 d][64 c'] PERMUTED
    __bf16* __restrict__ dst,
    float* __restrict__ stat_out)        // NCOPY x 128
{
    __shared__ char Bw[2][8192];

    const int tid  = threadIdx.x;
    const int lane = tid & 63;
    const int wv   = tid >> 6;
    const int quad = lane >> 4;
    const int l15  = lane & 15;
    const int row0 = blockIdx.x << 7;
    const int srow = tid >> 3;
    const int cg   = (tid & 7) ^ (srow & 7);
    const int ldsl = (tid & 192) << 4;
    const int sxor = l15 & 7;

    const char* wtb = (const char*)wt;

    f32x4_t acc[2][4];
#pragma unroll
    for (int mt = 0; mt < 2; ++mt)
#pragma unroll
        for (int nt = 0; nt < 4; ++nt)
            acc[mt][nt] = (f32x4_t){0.f, 0.f, 0.f, 0.f};

    const int ibase = row0 + (wv << 5) + l15;
    const unsigned qofs = (unsigned)(quad << 4);

    // prologue: idx k=0,1; stage B0; A0 (row + scale)
    int ixv[2][2];
#pragma unroll
    for (int mt = 0; mt < 2; ++mt) ixv[0][mt] = cidxT[ibase + (mt << 4)];
#pragma unroll
    for (int mt = 0; mt < 2; ++mt) ixv[1][mt] = cidxT[NROWS + ibase + (mt << 4)];
    CFENCE();
#pragma unroll
    for (int i = 0; i < 2; ++i)
        GLDS16(wtb + (((i << 5) + srow) << 7) + (cg << 4),
               &Bw[0][(i << 12) + ldsl]);
    CFENCE();
    i32x4_t areg[2][2];
    float   sfr[2][2];
#pragma unroll
    for (int mt = 0; mt < 2; ++mt) {
        int ix = ixv[0][mt];
        sfr[0][mt]  = sxa[ix];
        areg[0][mt] = *(const i32x4_t*)(srcq + ((size_t)(unsigned)ix << 6) + qofs);
    }
    CFENCE();

    // k-loop: idx[k+2] | stage B[k+1] | A[k+1](row+scale) | wait | barrier |
    // dequant + MFMA k | lgkm0 | barrier. 8 loads/iter -> 12/10/4.
#pragma unroll
    for (int k = 0; k < 9; ++k) {
        if (k < 7) {
#pragma unroll
            for (int mt = 0; mt < 2; ++mt)
                ixv[k & 1][mt] = cidxT[(k + 2) * NROWS + ibase + (mt << 4)];
        }
        CFENCE();
        if (k < 8) {
#pragma unroll
            for (int i = 0; i < 2; ++i)
                GLDS16(wtb + ((size_t)(k + 1) << 13)
                           + (((i << 5) + srow) << 7) + (cg << 4),
                       &Bw[(k + 1) & 1][(i << 12) + ldsl]);
        }
        CFENCE();
        if (k < 8) {
#pragma unroll
            for (int mt = 0; mt < 2; ++mt) {
                int ix = ixv[(k + 1) & 1][mt];
                sfr[(k + 1) & 1][mt]  = sxa[ix];
                areg[(k + 1) & 1][mt] =
                    *(const i32x4_t*)(srcq + ((size_t)(unsigned)ix << 6) + qofs);
            }
        }
        CFENCE();
        if (k < 7)       asm volatile("s_waitcnt vmcnt(12)" ::: "memory");
        else if (k == 7) asm volatile("s_waitcnt vmcnt(10)" ::: "memory");
        else             asm volatile("s_waitcnt vmcnt(4)"  ::: "memory");
        __builtin_amdgcn_s_barrier();
        bf16x8_t bq[4][2];
#pragma unroll
        for (int ks = 0; ks < 2; ++ks) {
            const int slot = ((quad | (ks << 2)) ^ sxor) << 4;
#pragma unroll
            for (int nt = 0; nt < 4; ++nt)
                bq[nt][ks] = *(const bf16x8_t*)
                    &Bw[k & 1][(((nt << 4) + l15) << 7) + slot];
        }
        bf16x8_t ta[2][2];
#pragma unroll
        for (int mt = 0; mt < 2; ++mt)
            dequant16(areg[k & 1][mt], sfr[k & 1][mt], ta[mt][0], ta[mt][1]);
        __builtin_amdgcn_s_setprio(1);
#pragma unroll
        for (int ks = 0; ks < 2; ++ks)
#pragma unroll
            for (int mt = 0; mt < 2; ++mt)
#pragma unroll
                for (int nt = 0; nt < 4; ++nt)
                    acc[mt][nt] = __builtin_amdgcn_mfma_f32_16x16x32_bf16(
                        ta[mt][ks], bq[nt][ks], acc[mt][nt], 0, 0, 0);
        __builtin_amdgcn_s_setprio(0);
        CFENCE();
        asm volatile("s_waitcnt lgkmcnt(0)" ::: "memory");
        __builtin_amdgcn_s_barrier();
        CFENCE();
    }

#pragma unroll
    for (int mt = 0; mt < 2; ++mt) {
        int rowb = row0 + (wv << 5) + (mt << 4) + (quad << 2);
#pragma unroll
        for (int nt = 0; nt < 4; ++nt) {
            int col = (nt << 4) + l15;
#pragma unroll
            for (int r = 0; r < 4; ++r)
                dst[((size_t)(rowb + r) << 6) + col] = (__bf16)acc[mt][nt][r];
        }
    }
    float* red = (float*)Bw;
    __syncthreads();
    if (tid < 128) red[tid] = 0.f;
    __syncthreads();
#pragma unroll
    for (int nt = 0; nt < 4; ++nt) {
        float s = 0.f, q = 0.f;
#pragma unroll
        for (int mt = 0; mt < 2; ++mt)
#pragma unroll
            for (int r = 0; r < 4; ++r) { float v = acc[mt][nt][r]; s += v; q += v * v; }
        s += __shfl_xor(s, 16); s += __shfl_xor(s, 32);
        q += __shfl_xor(q, 16); q += __shfl_xor(q, 32);
        if (lane < 16) {
            atomicAdd(&red[(nt << 4) + lane], s);
            atomicAdd(&red[64 + (nt << 4) + lane], q);
        }
    }
    __syncthreads();
    if (tid < 128)
        atomicAdd(&stat_out[((blockIdx.x & (NCOPY - 1)) << 7) + tid], red[tid]);
}

// ---- conv2 with fused BN1+leaky on the gathered A operand (r9 verbatim) ----
__global__ __launch_bounds__(256, 4) void convbn_kernel(
    const __bf16* __restrict__ src,
    const int* __restrict__ cidxT,
    const __bf16* __restrict__ wt,       // wtp2: STANDARD layout
    __bf16* __restrict__ dst,
    float* __restrict__ stat_out,
    const float* __restrict__ stat_in,
    const float* __restrict__ gamma, const float* __restrict__ beta)
{
    __shared__ char Bw[2][8192];
    __shared__ float scsh[128];
    __shared__ float scD[64], shD[64];

    const int tid  = threadIdx.x;
    const int lane = tid & 63;
    const int wv   = tid >> 6;
    const int quad = lane >> 4;
    const int l15  = lane & 15;
    const int row0 = blockIdx.x << 7;
    const int srow = tid >> 3;
    const int cg   = (tid & 7) ^ (srow & 7);
    const int ldsl = (tid & 192) << 4;
    const int sxor = l15 & 7;

    const char* srcb = (const char*)src;
    const char* wtb  = (const char*)wt;

    f32x4_t acc[2][4];
#pragma unroll
    for (int mt = 0; mt < 2; ++mt)
#pragma unroll
        for (int nt = 0; nt < 4; ++nt)
            acc[mt][nt] = (f32x4_t){0.f, 0.f, 0.f, 0.f};

    const int ibase = row0 + (wv << 5) + l15;
    const unsigned qofs = (unsigned)(quad << 4);

    int ixv[2][2], ixs[2][2];
#pragma unroll
    for (int mt = 0; mt < 2; ++mt) ixv[0][mt] = cidxT[ibase + (mt << 4)];
#pragma unroll
    for (int mt = 0; mt < 2; ++mt) ixv[1][mt] = cidxT[NROWS + ibase + (mt << 4)];
    CFENCE();
#pragma unroll
    for (int i = 0; i < 2; ++i)
        GLDS16(wtb + (((i << 5) + srow) << 7) + (cg << 4),
               &Bw[0][(i << 12) + ldsl]);
    CFENCE();
    if (tid < 128) {
        float s = 0.f;
#pragma unroll
        for (int c = 0; c < NCOPY; ++c) s += stat_in[(c << 7) + tid];
        scsh[tid] = s;
    }
    __syncthreads();
    if (tid < 64) {
        float m = scsh[tid] * (1.f / NROWS);
        float v = scsh[64 + tid] * (1.f / NROWS) - m * m;
        float s = gamma[tid] * rsqrtf(v + EPSBN);
        scD[tid] = s;
        shD[tid] = beta[tid] - m * s;
    }
    __syncthreads();
    asm volatile("s_waitcnt vmcnt(0)" ::: "memory");
    __builtin_amdgcn_s_barrier();
    CFENCE();

    bf16x8_t areg[2][2][2];
#pragma unroll
    for (int mt = 0; mt < 2; ++mt) {
        ixs[0][mt] = ixv[0][mt];
        unsigned vo = ((unsigned)ixv[0][mt] << 7) + qofs;
#pragma unroll
        for (int ks = 0; ks < 2; ++ks)
            areg[0][mt][ks] = *(const bf16x8_t*)(srcb + vo + (ks << 6));
    }
    CFENCE();

#pragma unroll
    for (int k = 0; k < 9; ++k) {
        if (k < 7) {
#pragma unroll
            for (int mt = 0; mt < 2; ++mt)
                ixv[k & 1][mt] = cidxT[(k + 2) * NROWS + ibase + (mt << 4)];
        }
        CFENCE();
        if (k < 8) {
#pragma unroll
            for (int i = 0; i < 2; ++i)
                GLDS16(wtb + ((size_t)(k + 1) << 13)
                           + (((i << 5) + srow) << 7) + (cg << 4),
                       &Bw[(k + 1) & 1][(i << 12) + ldsl]);
        }
        CFENCE();
        if (k < 8) {
#pragma unroll
            for (int mt = 0; mt < 2; ++mt) {
                int ix = ixv[(k + 1) & 1][mt];
                ixs[(k + 1) & 1][mt] = ix;
                unsigned vo = ((unsigned)ix << 7) + qofs;
#pragma unroll
                for (int ks = 0; ks < 2; ++ks)
                    areg[(k + 1) & 1][mt][ks] =
                        *(const bf16x8_t*)(srcb + vo + (ks << 6));
            }
        }
        CFENCE();
        if (k < 7)       asm volatile("s_waitcnt vmcnt(12)" ::: "memory");
        else if (k == 7) asm volatile("s_waitcnt vmcnt(10)" ::: "memory");
        else             asm volatile("s_waitcnt vmcnt(4)"  ::: "memory");
        __builtin_amdgcn_s_barrier();
        f32x4_t scq[2][2], shq[2][2];
#pragma unroll
        for (int ks = 0; ks < 2; ++ks) {
            int cb = (ks << 5) + (quad << 3);
            scq[ks][0] = *(const f32x4_t*)&scD[cb];
            scq[ks][1] = *(const f32x4_t*)&scD[cb + 4];
            shq[ks][0] = *(const f32x4_t*)&shD[cb];
            shq[ks][1] = *(const f32x4_t*)&shD[cb + 4];
        }
        bf16x8_t ta[2][2];
        const bf16x8_t zfrag = {};
#pragma unroll
        for (int mt = 0; mt < 2; ++mt) {
            bool dead = (ixs[k & 1][mt] == NROWS);
#pragma unroll
            for (int ks = 0; ks < 2; ++ks) {
                bf16x8_t a = areg[k & 1][mt][ks];
                bf16x8_t t;
#pragma unroll
                for (int j = 0; j < 8; ++j) {
                    float f = (float)a[j];
                    float y = fmaf(scq[ks][j >> 2][j & 3], f,
                                   shq[ks][j >> 2][j & 3]);
                    y = fmaxf(y, LEAKK * y);
                    t[j] = (__bf16)y;
                }
                ta[mt][ks] = dead ? zfrag : t;
            }
        }
        bf16x8_t bq[4][2];
#pragma unroll
        for (int ks = 0; ks < 2; ++ks) {
            const int slot = ((quad | (ks << 2)) ^ sxor) << 4;
#pragma unroll
            for (int nt = 0; nt < 4; ++nt)
                bq[nt][ks] = *(const bf16x8_t*)
                    &Bw[k & 1][(((nt << 4) + l15) << 7) + slot];
        }
        __builtin_amdgcn_s_setprio(1);
#pragma unroll
        for (int ks = 0; ks < 2; ++ks)
#pragma unroll
            for (int mt = 0; mt < 2; ++mt)
#pragma unroll
                for (int nt = 0; nt < 4; ++nt)
                    acc[mt][nt] = __builtin_amdgcn_mfma_f32_16x16x32_bf16(
                        ta[mt][ks], bq[nt][ks], acc[mt][nt], 0, 0, 0);
        __builtin_amdgcn_s_setprio(0);
        CFENCE();
        asm volatile("s_waitcnt lgkmcnt(0)" ::: "memory");
        __builtin_amdgcn_s_barrier();
        CFENCE();
    }

#pragma unroll
    for (int mt = 0; mt < 2; ++mt) {
        int rowb = row0 + (wv << 5) + (mt << 4) + (quad << 2);
#pragma unroll
        for (int nt = 0; nt < 4; ++nt) {
            int col = (nt << 4) + l15;
#pragma unroll
            for (int r = 0; r < 4; ++r)
                dst[((size_t)(rowb + r) << 6) + col] = (__bf16)acc[mt][nt][r];
        }
    }
    float* red = (float*)Bw;
    __syncthreads();
    if (tid < 128) red[tid] = 0.f;
    __syncthreads();
#pragma unroll
    for (int nt = 0; nt < 4; ++nt) {
        float s = 0.f, q = 0.f;
#pragma unroll
        for (int mt = 0; mt < 2; ++mt)
#pragma unroll
            for (int r = 0; r < 4; ++r) { float v = acc[mt][nt][r]; s += v; q += v * v; }
        s += __shfl_xor(s, 16); s += __shfl_xor(s, 32);
        q += __shfl_xor(q, 16); q += __shfl_xor(q, 32);
        if (lane < 16) {
            atomicAdd(&red[(nt << 4) + lane], s);
            atomicAdd(&red[64 + (nt << 4) + lane], q);
        }
    }
    __syncthreads();
    if (tid < 128)
        atomicAdd(&stat_out[((blockIdx.x & (NCOPY - 1)) << 7) + tid], red[tid]);
}

// x_new = leaky(bn2(z)+x); writes bf16 xh AND int8 xq + per-row scale sxa
__global__ __launch_bounds__(256) void resid_kernel(
    const __bf16* __restrict__ z, const float* __restrict__ featin,
    __bf16* __restrict__ xh, char* __restrict__ xq, float* __restrict__ sxa,
    float* __restrict__ dout,
    const float* __restrict__ stat, const float* __restrict__ gamma,
    const float* __restrict__ beta, int isfirst, int isfinal)
{
    __shared__ float sc[64], sh[64];
    int tid = threadIdx.x;
    if (tid < 128) {
        float s = 0.f;
#pragma unroll
        for (int c = 0; c < NCOPY; ++c) s += stat[(c << 7) + tid];
        if (tid < 64) sc[tid] = s;
        else          sh[tid - 64] = s;
    }
    __syncthreads();
    if (tid < 64) {
        float m = sc[tid] * (1.f / NROWS);
        float v = sh[tid] * (1.f / NROWS) - m * m;
        float s = gamma[tid] * rsqrtf(v + EPSBN);
        sc[tid] = s;
        sh[tid] = beta[tid] - m * s;
    }
    __syncthreads();
    size_t base = ((((size_t)blockIdx.x << 8) | tid) << 3);
    int c0 = (int)(base & 63);
    bf16x8_t zv = *(const bf16x8_t*)(z + base);
    float xv[8];
    if (isfirst) {
        float4 xa = *(const float4*)(featin + base);
        float4 xb = *(const float4*)(featin + base + 4);
#pragma unroll
        for (int j = 0; j < 4; ++j) { xv[j] = (&xa.x)[j]; xv[4 + j] = (&xb.x)[j]; }
    } else {
        bf16x8_t xr = *(const bf16x8_t*)(xh + base);
#pragma unroll
        for (int j = 0; j < 8; ++j) xv[j] = (float)xr[j];
    }
    float o[8];
#pragma unroll
    for (int j = 0; j < 8; ++j)
        o[j] = leaky_f((float)zv[j] * sc[c0 + j] + sh[c0 + j] + xv[j]);
    if (isfinal) {
        *(float4*)(dout + base)     = make_float4(o[0], o[1], o[2], o[3]);
        *(float4*)(dout + base + 4) = make_float4(o[4], o[5], o[6], o[7]);
    } else {
        bf16x8_t h;
        float mx = 1e-6f;
#pragma unroll
        for (int j = 0; j < 8; ++j) { h[j] = (__bf16)o[j]; mx = fmaxf(mx, fabsf(o[j])); }
        mx = fmaxf(mx, __shfl_xor(mx, 1));
        mx = fmaxf(mx, __shfl_xor(mx, 2));
        mx = fmaxf(mx, __shfl_xor(mx, 4));
        float qs = 127.f / mx;
        unsigned long long pk = 0;
#pragma unroll
        for (int j = 0; j < 8; ++j) {
            int q = (int)rintf(o[j] * qs);
            pk |= ((unsigned long long)(unsigned char)(signed char)q) << (j << 3);
        }
        *(bf16x8_t*)(xh + base) = h;
        *(unsigned long long*)(xq + base) = pk;
        if ((tid & 7) == 0) sxa[base >> 6] = mx * (1.f / 127.f);
    }
}

// prep: feat->int8 xq + sxa, w2->wtp2 (std), w1->wtp1 (PERMUTED), stats,
// cidxT, sentinel rows/scale.
__global__ __launch_bounds__(256) void prep_kernel(
    const float* __restrict__ feat, const float* __restrict__ w1,
    const float* __restrict__ w2, const int* __restrict__ nidx,
    const unsigned char* __restrict__ mraw,
    __bf16* __restrict__ yh, char* __restrict__ xq, float* __restrict__ sxa,
    __bf16* __restrict__ wtp2, __bf16* __restrict__ wtp1,
    int* __restrict__ cidxT, float* __restrict__ stats)
{
    size_t t = ((size_t)blockIdx.x << 8) | threadIdx.x;
    if (t < 8192) stats[t] = 0.f;
    if (t < 64) {   // sentinel rows
        yh[(size_t)NROWS * 64 + t] = (__bf16)0.f;
        xq[(size_t)NROWS * 64 + t] = 0;
        if (t == 0) sxa[NROWS] = 1.f;
    }
    if (t < 1048576) {  // features: 8 floats -> 8 int8 + row scale
        size_t i = t << 3;
        float4 a = *(const float4*)(feat + i);
        float4 b = *(const float4*)(feat + i + 4);
        float o[8] = {a.x, a.y, a.z, a.w, b.x, b.y, b.z, b.w};
        float mx = 1e-6f;
#pragma unroll
        for (int j = 0; j < 8; ++j) mx = fmaxf(mx, fabsf(o[j]));
        mx = fmaxf(mx, __shfl_xor(mx, 1));
        mx = fmaxf(mx, __shfl_xor(mx, 2));
        mx = fmaxf(mx, __shfl_xor(mx, 4));
        float qs = 127.f / mx;
        unsigned long long pk = 0;
#pragma unroll
        for (int j = 0; j < 8; ++j) {
            int q = (int)rintf(o[j] * qs);
            pk |= ((unsigned long long)(unsigned char)(signed char)q) << (j << 3);
        }
        *(unsigned long long*)(xq + i) = pk;
        if ((threadIdx.x & 7) == 0) sxa[i >> 6] = mx * (1.f / 127.f);
    }
    if (t < 294912) {   // weights: first half wtp2 std, second half wtp1 perm
        int o = (int)t;
        int cc = o & 63, d = (o >> 6) & 63;
        int kk = o >> 12;              // 0..71
        int k = kk % 9, bb = (kk / 9) & 3, cv = kk / 36;
        if (cv == 0) {
            float v = w2[((size_t)((bb * 9 + k) * 64 + cc) << 6) + d];
            wtp2[o] = (__bf16)v;
        } else {
            int o1 = o - 147456;
            int ch = (cc & 7) + (((cc >> 3) & 3) << 4) + (((cc >> 5) & 1) << 3);
            float v = w1[((size_t)((bb * 9 + k) * 64 + ch) << 6) + d];
            wtp1[o1] = (__bf16)v;
        }
    }
    if (t < NROWS) {    // cidxT: one thread per row n, 9 entries
        int n = (int)t;
        bool benc = (mraw[13] != 0);
        const unsigned int* mw = (const unsigned int*)mraw;
#pragma unroll
        for (int j = 0; j < 9; ++j) {
            int e = n * 9 + j;
            bool m = benc ? (mraw[e] != 0) : (mw[e] != 0u);
            cidxT[j * NROWS + n] = m ? nidx[e] : NROWS;
        }
    }
}

extern "C" void kernel_launch(void* const* d_in, const int* in_sizes, int n_in,
                              void* d_out, int out_size, void* d_ws, size_t ws_size,
                              hipStream_t stream) {
    const float* feat = (const float*)d_in[0];
    const int* nidx = (const int*)d_in[1];
    const unsigned char* mraw = (const unsigned char*)d_in[2];
    const float* w1 = (const float*)d_in[3];
    const float* g1 = (const float*)d_in[4];
    const float* b1 = (const float*)d_in[5];
    const float* w2 = (const float*)d_in[6];
    const float* g2 = (const float*)d_in[7];
    const float* b2 = (const float*)d_in[8];
    float* out = (float*)d_out;

    char* ws = (char*)d_ws;
    __bf16* xh    = (__bf16*)ws;                       // (N+1)x64 bf16 residual
    __bf16* yh    = (__bf16*)(ws + 17825792);          // (N+1)x64 bf16 conv1 raw
    __bf16* zh    = (__bf16*)(ws + 35651584);          // N x64 bf16 conv2 raw
    __bf16* wtp2  = (__bf16*)(ws + 53477376);          // w2 bf16 std layout
    __bf16* wtp1  = (__bf16*)(ws + 53772288);          // w1 bf16 PERMUTED
    float*  stats = (float*)(ws + 54525952);           // 8 stages x 1024 floats
    int*    cidxT = (int*)(ws + 54591488);             // 4.72 MB premasked idx^T
    char*   xq    = ws + 59310080;                     // (N+1)x64 int8 table
    float*  sxa   = (float*)(ws + 67698752);           // (N+1) row scales

    prep_kernel<<<4096, 256, 0, stream>>>(feat, w1, w2, nidx, mraw,
                                          yh, xq, sxa, wtp2, wtp1, cidxT, stats);

    for (int b = 0; b < 4; ++b) {
        // conv1: int8+scale gather, bf16 MFMA -> yh raw + stats(2b)
        convq_kernel<<<1024, 256, 0, stream>>>(
            xq, sxa, cidxT, wtp1 + (size_t)b * 36864,
            yh, stats + (size_t)(2 * b) * 1024);
        // conv2: bf16 gather, fused BN1+leaky on A -> zh raw + stats(2b+1)
        convbn_kernel<<<1024, 256, 0, stream>>>(
            yh, cidxT, wtp2 + (size_t)b * 36864,
            zh, stats + (size_t)(2 * b + 1) * 1024,
            stats + (size_t)(2 * b) * 1024, g1 + b * 64, b1 + b * 64);
        // resid: x_new = leaky(bn2(z)+x) -> xh bf16 + xq/sxa int8 (or out)
        resid_kernel<<<4096, 256, 0, stream>>>(
            zh, feat, xh, xq, sxa, out,
            stats + (size_t)(2 * b + 1) * 1024, g2 + b * 64, b2 + b * 64,
            (b == 0) ? 1 : 0, (b == 3) ? 1 : 0);
    }
}